// Round 3
// baseline (816.715 us; speedup 1.0000x reference)
//
#include <hip/hip_runtime.h>

#define VSZ 50257
#define DSZ 1024
#define TSZ 512
#define BSZ 4
#define HSZ 4096
#define VPAD 50304   // 393*128
#define NCH (VPAD / 64)   // 786 v-stripes of 64
#define NPOS 2048

typedef __attribute__((ext_vector_type(8))) __bf16 bf16x8;
typedef __attribute__((ext_vector_type(4))) float f32x4;

#define GLD16(gp, lp) __builtin_amdgcn_global_load_lds( \
  (const __attribute__((address_space(1))) unsigned int*)(gp), \
  (__attribute__((address_space(3))) unsigned int*)(lp), 16, 0, 0)

__device__ __forceinline__ float gelu_f(float x) {
  float x3 = x * x * x;
  float u = 0.7978845608028654f * (x + 0.044715f * x3);
  return 0.5f * x * (1.f + tanhf(u));
}

// -------- transpose + f32->bf16: src (R x C) -> dst (Cpad x R); 64x64 tiles,
// coalesced 256B row reads (wave = one row), 128B ushort4 row writes.
__global__ __launch_bounds__(256) void transpose_conv64(const float* __restrict__ src,
                                                        __bf16* __restrict__ dst,
                                                        int R, int C, int Cpad) {
  __shared__ float tile[64][65];
  int c0 = blockIdx.x * 64, r0 = blockIdx.y * 64;
  int tid = threadIdx.x;
  int wv = tid >> 6, ln = tid & 63;
  int c = c0 + ln;
#pragma unroll 4
  for (int i = 0; i < 16; ++i) {
    int r = i * 4 + wv;
    tile[r][ln] = (c < C) ? src[(size_t)(r0 + r) * C + c] : 0.f;
  }
  __syncthreads();
  int ccb = tid >> 4;          // 0..15, +j*16
  int r4 = (tid & 15) * 4;     // row quad
#pragma unroll
  for (int j = 0; j < 4; ++j) {
    int cc = ccb + j * 16;
    union { ushort4 u4; ushort s[4]; } pk;
#pragma unroll
    for (int q = 0; q < 4; ++q) {
      union { __bf16 b; ushort s; } cv;
      cv.b = (__bf16)tile[r4 + q][cc];
      pk.s[q] = cv.s;
    }
    *(ushort4*)(dst + (size_t)(c0 + cc) * R + r0 + r4) = pk.u4;
  }
}

// -------- encoder layer 1 partials: K-split dot over d-chunk of 128
#define KS1 8
__global__ __launch_bounds__(256) void enc1p_kernel(const int* __restrict__ ids,
                                                    const float* __restrict__ wte,
                                                    const float* __restrict__ w1,
                                                    float* __restrict__ t1p) {
  int b = blockIdx.x;
  int h = blockIdx.y * 256 + threadIdx.x;
  int kc = blockIdx.z;
  int tok = ids[b * TSZ + (TSZ - 1)];
  const float* ev = wte + (size_t)tok * DSZ + kc * (DSZ / KS1);
  const float* w = w1 + (size_t)kc * (DSZ / KS1) * HSZ + h;
  float s = 0.f;
#pragma unroll 4
  for (int d = 0; d < DSZ / KS1; ++d) s += ev[d] * w[(size_t)d * HSZ];
  t1p[((size_t)(b * KS1 + kc)) * HSZ + h] = s;
}

// -------- encoder layer 2 partials (enc1 combine + gelu fused in):
#define KS2 16
__global__ __launch_bounds__(256) void enc2p_kernel(const float* __restrict__ t1p,
                                                    const float* __restrict__ b1,
                                                    const float* __restrict__ w2,
                                                    float* __restrict__ ep) {
  __shared__ float ts[256];   // HSZ/KS2
  int b = blockIdx.x;
  int i = blockIdx.y * 256 + threadIdx.x;
  int kc = blockIdx.z;
  int h = kc * 256 + threadIdx.x;
  float s0 = b1[h];
#pragma unroll
  for (int cc = 0; cc < KS1; ++cc) s0 += t1p[((size_t)(b * KS1 + cc)) * HSZ + h];
  ts[threadIdx.x] = gelu_f(s0);
  __syncthreads();
  const float* w = w2 + (size_t)kc * 256 * DSZ + i;
  float s = 0.f;
#pragma unroll 4
  for (int j = 0; j < 256; ++j) s += ts[j] * w[(size_t)j * DSZ];
  ep[((size_t)(b * KS2 + kc)) * DSZ + i] = s;
}

__global__ __launch_bounds__(256) void enc2c_kernel(const float* __restrict__ ep,
                                                    const float* __restrict__ b2,
                                                    float* __restrict__ e) {
  int idx = blockIdx.x * 256 + threadIdx.x;   // b*DSZ + i
  int b = idx >> 10, i = idx & (DSZ - 1);
  float s = b2[i];
#pragma unroll
  for (int kc = 0; kc < KS2; ++kc) s += ep[((size_t)(b * KS2 + kc)) * DSZ + i];
  e[idx] = s;
}

// -------- windows: win[b*T+t][j] = bf16(e[b][t+j])   (t+j < 1024 always)
__global__ void win_kernel(const float* __restrict__ e, __bf16* __restrict__ win) {
  int blk = blockIdx.x;               // b*512 + t
  int b = blk >> 9, t = blk & 511;
  const float* eb = e + b * DSZ;
  for (int j = threadIdx.x; j < 512; j += 256)
    win[(size_t)blk * 512 + j] = (__bf16)eb[t + j];
}

// -------- GEMM: C[m][n] = sum_k A[m][k]*B[n][k]  (both operands K-contiguous)
// BK=64, both-sides LDS XOR swizzle ((row&7)<<4), XCD-swizzled 1D grid.
// MODE 0: out bf16 row-major [M][N], + bias[n], optional gelu
// MODE 1: lm head: m=v, n=b*T+t -> outF[1 + b*V*T + v*T + t], guard v<VSZ,
//         fused softmax partials per 64-v stripe
template<int MODE, int GELU>
__global__ __launch_bounds__(256) void gemm128(
    const __bf16* __restrict__ A, const __bf16* __restrict__ Bm,
    const float* __restrict__ bias, __bf16* __restrict__ outB,
    float* __restrict__ outF, float* __restrict__ pm, float* __restrict__ ps,
    int NT, int M, int N, int K) {
  __shared__ __bf16 smA[128 * 64];
  __shared__ __bf16 smB[128 * 64];
  const int tid = threadIdx.x;
  const int lane = tid & 63;
  const int wave = tid >> 6;
  const int wr = (wave >> 1) * 64, wc = (wave & 1) * 64;
  const int l15 = lane & 15, l4 = lane >> 4;

  // XCD-aware block swizzle (gridDim.x always divisible by 8 here)
  const int cpx = gridDim.x >> 3;
  const int wg = (blockIdx.x & 7) * cpx + (blockIdx.x >> 3);
  const int m0 = (wg / NT) * 128, n0 = (wg % NT) * 128;

  f32x4 acc[4][4];
#pragma unroll
  for (int i = 0; i < 4; ++i)
#pragma unroll
    for (int j = 0; j < 4; ++j) acc[i][j] = (f32x4){0.f, 0.f, 0.f, 0.f};

  // staging: 4 chunks of 16B per thread per matrix; linear LDS dest,
  // inverse-swizzled global source (rule: both-sides-or-neither)
  const int lrow = tid >> 3;            // row within 32-row chunk
  const int cb = (tid & 7) * 16;        // linear col byte
  const int scb = cb ^ ((lrow & 7) << 4); // swizzled source col byte
  const __bf16* srcA[4];
  const __bf16* srcB[4];
#pragma unroll
  for (int c = 0; c < 4; ++c) {
    int row = c * 32 + lrow;
    srcA[c] = A + (size_t)(m0 + row) * K + (scb >> 1);
    srcB[c] = Bm + (size_t)(n0 + row) * K + (scb >> 1);
  }

  const int swzr = (lane & 7) << 4;     // read-side XOR (row&7 == lane&7)

  for (int k0 = 0; k0 < K; k0 += 64) {
#pragma unroll
    for (int c = 0; c < 4; ++c) {
      GLD16(srcA[c], (char*)smA + c * 4096 + wave * 1024);
      GLD16(srcB[c], (char*)smB + c * 4096 + wave * 1024);
      srcA[c] += 64; srcB[c] += 64;
    }
    __syncthreads();
#pragma unroll
    for (int kk = 0; kk < 2; ++kk) {
      const int cbase = (kk * 64 + l4 * 16) ^ swzr;
      bf16x8 af[4], bfr[4];
#pragma unroll
      for (int mi = 0; mi < 4; ++mi)
        af[mi] = *(const bf16x8*)((const char*)smA + (wr + mi * 16 + l15) * 128 + cbase);
#pragma unroll
      for (int ni = 0; ni < 4; ++ni)
        bfr[ni] = *(const bf16x8*)((const char*)smB + (wc + ni * 16 + l15) * 128 + cbase);
#pragma unroll
      for (int mi = 0; mi < 4; ++mi)
#pragma unroll
        for (int ni = 0; ni < 4; ++ni)
          acc[mi][ni] = __builtin_amdgcn_mfma_f32_16x16x32_bf16(af[mi], bfr[ni], acc[mi][ni], 0, 0, 0);
    }
    __syncthreads();
  }

  if (MODE == 0) {
#pragma unroll
    for (int ni = 0; ni < 4; ++ni) {
      int n = n0 + wc + ni * 16 + l15;
      float bv = bias[n];
#pragma unroll
      for (int mi = 0; mi < 4; ++mi) {
#pragma unroll
        for (int r = 0; r < 4; ++r) {
          int m = m0 + wr + mi * 16 + l4 * 4 + r;
          float v = acc[mi][ni][r] + bv;
          if (GELU) v = gelu_f(v);
          outB[(size_t)m * N + n] = (__bf16)v;
        }
      }
    }
  } else {
    const int ch = (m0 + wr) >> 6;   // global 64-v stripe index
#pragma unroll
    for (int ni = 0; ni < 4; ++ni) {
      int n = n0 + wc + ni * 16 + l15;   // pos = b*T + t
      int bb = n >> 9, tt = n & 511;
      float mloc = -1e30f, sloc = 0.f;
#pragma unroll
      for (int mi = 0; mi < 4; ++mi) {
        int vbase = m0 + wr + mi * 16 + l4 * 4;
#pragma unroll
        for (int r = 0; r < 4; ++r) {
          int v = vbase + r;
          if (v < VSZ) {
            float x = acc[mi][ni][r];
            outF[1 + (size_t)bb * VSZ * TSZ + (size_t)v * TSZ + tt] = x;
            mloc = fmaxf(mloc, x);
          }
        }
      }
#pragma unroll
      for (int mi = 0; mi < 4; ++mi) {
        int vbase = m0 + wr + mi * 16 + l4 * 4;
#pragma unroll
        for (int r = 0; r < 4; ++r) {
          if (vbase + r < VSZ) sloc += __expf(acc[mi][ni][r] - mloc);
        }
      }
#pragma unroll
      for (int off = 16; off <= 32; off <<= 1) {
        float mo = __shfl_xor(mloc, off, 64);
        float so = __shfl_xor(sloc, off, 64);
        float nm = fmaxf(mloc, mo);
        sloc = sloc * __expf(mloc - nm) + so * __expf(mo - nm);
        mloc = nm;
      }
      if (l4 == 0) {
        pm[(size_t)ch * NPOS + n] = mloc;
        ps[(size_t)ch * NPOS + n] = sloc;
      }
    }
  }
}

// -------- merge softmax partials per position, gather label logit
__global__ __launch_bounds__(256) void lsemerge_kernel(const float* __restrict__ pm,
                                                       const float* __restrict__ ps,
                                                       const float* __restrict__ outF,
                                                       const int* __restrict__ labels,
                                                       float* __restrict__ contrib) {
  int pos = blockIdx.x * 256 + threadIdx.x;   // 0..2047
  float m = -1e30f, s = 0.f;
  for (int c = 0; c < NCH; ++c) {
    float cm = pm[(size_t)c * NPOS + pos];
    float cs = ps[(size_t)c * NPOS + pos];
    float nm = fmaxf(m, cm);
    s = s * __expf(m - nm) + cs * __expf(cm - nm);
    m = nm;
  }
  float lse = m + logf(s);
  int b = pos >> 9, t = pos & 511;
  int lab = labels[pos];
  float x = outF[1 + (size_t)b * VSZ * TSZ + (size_t)lab * TSZ + t];
  contrib[pos] = lse - x;
}

__global__ __launch_bounds__(256) void lossfinal_kernel(const float* __restrict__ contrib,
                                                        float* __restrict__ dout) {
  __shared__ float red[256];
  int tid = threadIdx.x;
  float a = 0.f;
  for (int i = tid; i < NPOS; i += 256) a += contrib[i];
  red[tid] = a;
  __syncthreads();
  for (int off = 128; off; off >>= 1) {
    if (tid < off) red[tid] += red[tid + off];
    __syncthreads();
  }
  if (tid == 0) dout[0] = red[0] / (float)NPOS;
}

extern "C" void kernel_launch(void* const* d_in, const int* in_sizes, int n_in,
                              void* d_out, int out_size, void* d_ws, size_t ws_size,
                              hipStream_t stream) {
  const int* input_ids = (const int*)d_in[0];
  const int* labels    = (const int*)d_in[1];
  const float* wte     = (const float*)d_in[2];
  const float* enc_w1  = (const float*)d_in[3];
  const float* enc_b1  = (const float*)d_in[4];
  const float* enc_w2  = (const float*)d_in[5];
  const float* enc_b2  = (const float*)d_in[6];
  const float* proj_w  = (const float*)d_in[7];
  const float* proj_b  = (const float*)d_in[8];
  const float* dec_w1  = (const float*)d_in[9];
  const float* dec_b1  = (const float*)d_in[10];
  const float* dec_w2  = (const float*)d_in[11];
  const float* dec_b2  = (const float*)d_in[12];
  const float* lm_w    = (const float*)d_in[13];
  float* outF = (float*)d_out;

  char* w = (char*)d_ws;
  size_t off = 0;
  __bf16* lmT   = (__bf16*)(w + off); off += (size_t)VPAD * DSZ * 2;      // 103.0 MB
  __bf16* w1T   = (__bf16*)(w + off); off += (size_t)HSZ * DSZ * 2;       // 8 MB
  __bf16* w2T   = (__bf16*)(w + off); off += (size_t)DSZ * HSZ * 2;       // 8 MB
  __bf16* projT = (__bf16*)(w + off); off += (size_t)DSZ * 512 * 2;       // 1 MB
  __bf16* win   = (__bf16*)(w + off); off += (size_t)2048 * 512 * 2;      // 2 MB
  __bf16* pbuf  = (__bf16*)(w + off); off += (size_t)2048 * DSZ * 2;      // 4 MB
  __bf16* abuf  = (__bf16*)(w + off); off += (size_t)2048 * HSZ * 2;      // 16 MB
  __bf16* dbuf  = (__bf16*)(w + off); off += (size_t)2048 * DSZ * 2;      // 4 MB
  float* e      = (float*)(w + off);  off += (size_t)BSZ * DSZ * 4;
  float* t1p    = (float*)(w + off);  off += (size_t)BSZ * KS1 * HSZ * 4;   // 512 KB
  float* ep     = (float*)(w + off);  off += (size_t)BSZ * KS2 * DSZ * 4;   // 256 KB
  float* contrib= (float*)(w + off);  off += (size_t)NPOS * 4;
  // softmax partials alias abuf (free after gemm3): 786*2048*4*2 = 12.9 MB <= 16 MB
  float* pm = (float*)abuf;
  float* ps = pm + (size_t)NCH * NPOS;
  (void)ws_size; (void)in_sizes; (void)n_in; (void)out_size;

  // weight transposes (f32 -> bf16, K-contiguous)
  transpose_conv64<<<dim3(VPAD / 64, DSZ / 64), 256, 0, stream>>>(lm_w, lmT, DSZ, VSZ, VPAD);
  transpose_conv64<<<dim3(HSZ / 64, DSZ / 64), 256, 0, stream>>>(dec_w1, w1T, DSZ, HSZ, HSZ);
  transpose_conv64<<<dim3(DSZ / 64, HSZ / 64), 256, 0, stream>>>(dec_w2, w2T, HSZ, DSZ, DSZ);
  transpose_conv64<<<dim3(DSZ / 64, 512 / 64), 256, 0, stream>>>(proj_w, projT, 512, DSZ, DSZ);

  // encoder on last token only (K-split for parallelism)
  enc1p_kernel<<<dim3(BSZ, HSZ / 256, KS1), 256, 0, stream>>>(input_ids, wte, enc_w1, t1p);
  enc2p_kernel<<<dim3(BSZ, DSZ / 256, KS2), 256, 0, stream>>>(t1p, enc_b1, enc_w2, ep);
  enc2c_kernel<<<dim3(BSZ * DSZ / 256), 256, 0, stream>>>(ep, enc_b2, e);
  win_kernel<<<2048, 256, 0, stream>>>(e, win);

  // GEMM chain (1D grids, all divisible by 8 for the XCD swizzle)
  gemm128<0, 0><<<128, 256, 0, stream>>>(win, projT, proj_b, pbuf, nullptr, nullptr, nullptr, 8, 2048, DSZ, 512);
  gemm128<0, 1><<<512, 256, 0, stream>>>(pbuf, w1T, dec_b1, abuf, nullptr, nullptr, nullptr, 32, 2048, HSZ, DSZ);
  gemm128<0, 0><<<128, 256, 0, stream>>>(abuf, w2T, dec_b2, dbuf, nullptr, nullptr, nullptr, 8, 2048, DSZ, HSZ);
  // lm head with fused softmax partials; grid = 393*16 = 6288, m = v-tiles
  gemm128<1, 0><<<6288, 256, 0, stream>>>(lmT, dbuf, nullptr, nullptr, outF, pm, ps, 16, VPAD, 2048, DSZ);

  // loss: merge partials + mean
  lsemerge_kernel<<<dim3(NPOS / 256), 256, 0, stream>>>(pm, ps, outF, labels, contrib);
  lossfinal_kernel<<<1, 256, 0, stream>>>(contrib, outF);
}

// Round 4
// 758.469 us; speedup vs baseline: 1.0768x; 1.0768x over previous
//
#include <hip/hip_runtime.h>

#define VSZ 50257
#define DSZ 1024
#define TSZ 512
#define BSZ 4
#define HSZ 4096
#define VPAD 50304   // 393*128
#define NCH (VPAD / 64)   // 786 v-stripes of 64
#define NPOS 2048

typedef __attribute__((ext_vector_type(8))) __bf16 bf16x8;
typedef __attribute__((ext_vector_type(4))) float f32x4;

#define GLD16(gp, lp) __builtin_amdgcn_global_load_lds( \
  (const __attribute__((address_space(1))) unsigned int*)(gp), \
  (__attribute__((address_space(3))) unsigned int*)(lp), 16, 0, 0)

__device__ __forceinline__ float gelu_f(float x) {
  float x3 = x * x * x;
  float u = 0.7978845608028654f * (x + 0.044715f * x3);
  return 0.5f * x * (1.f + tanhf(u));
}

// -------- transpose + f32->bf16: src (R x C) -> dst (Cpad x R); 64x64 tiles
__global__ __launch_bounds__(256) void transpose_conv64(const float* __restrict__ src,
                                                        __bf16* __restrict__ dst,
                                                        int R, int C, int Cpad) {
  __shared__ float tile[64][65];
  int c0 = blockIdx.x * 64, r0 = blockIdx.y * 64;
  int tid = threadIdx.x;
  int wv = tid >> 6, ln = tid & 63;
  int c = c0 + ln;
#pragma unroll 4
  for (int i = 0; i < 16; ++i) {
    int r = i * 4 + wv;
    tile[r][ln] = (c < C) ? src[(size_t)(r0 + r) * C + c] : 0.f;
  }
  __syncthreads();
  int ccb = tid >> 4;          // 0..15, +j*16
  int r4 = (tid & 15) * 4;     // row quad
#pragma unroll
  for (int j = 0; j < 4; ++j) {
    int cc = ccb + j * 16;
    union { ushort4 u4; ushort s[4]; } pk;
#pragma unroll
    for (int q = 0; q < 4; ++q) {
      union { __bf16 b; ushort s; } cv;
      cv.b = (__bf16)tile[r4 + q][cc];
      pk.s[q] = cv.s;
    }
    *(ushort4*)(dst + (size_t)(c0 + cc) * R + r0 + r4) = pk.u4;
  }
}

// -------- encoder layer 1 partials: K-split dot over d-chunk of 128
#define KS1 8
__global__ __launch_bounds__(256) void enc1p_kernel(const int* __restrict__ ids,
                                                    const float* __restrict__ wte,
                                                    const float* __restrict__ w1,
                                                    float* __restrict__ t1p) {
  int b = blockIdx.x;
  int h = blockIdx.y * 256 + threadIdx.x;
  int kc = blockIdx.z;
  int tok = ids[b * TSZ + (TSZ - 1)];
  const float* ev = wte + (size_t)tok * DSZ + kc * (DSZ / KS1);
  const float* w = w1 + (size_t)kc * (DSZ / KS1) * HSZ + h;
  float s = 0.f;
#pragma unroll 4
  for (int d = 0; d < DSZ / KS1; ++d) s += ev[d] * w[(size_t)d * HSZ];
  t1p[((size_t)(b * KS1 + kc)) * HSZ + h] = s;
}

// -------- encoder layer 2 partials (enc1 combine + gelu fused in):
#define KS2 16
__global__ __launch_bounds__(256) void enc2p_kernel(const float* __restrict__ t1p,
                                                    const float* __restrict__ b1,
                                                    const float* __restrict__ w2,
                                                    float* __restrict__ ep) {
  __shared__ float ts[256];   // HSZ/KS2
  int b = blockIdx.x;
  int i = blockIdx.y * 256 + threadIdx.x;
  int kc = blockIdx.z;
  int h = kc * 256 + threadIdx.x;
  float s0 = b1[h];
#pragma unroll
  for (int cc = 0; cc < KS1; ++cc) s0 += t1p[((size_t)(b * KS1 + cc)) * HSZ + h];
  ts[threadIdx.x] = gelu_f(s0);
  __syncthreads();
  const float* w = w2 + (size_t)kc * 256 * DSZ + i;
  float s = 0.f;
#pragma unroll 4
  for (int j = 0; j < 256; ++j) s += ts[j] * w[(size_t)j * DSZ];
  ep[((size_t)(b * KS2 + kc)) * DSZ + i] = s;
}

__global__ __launch_bounds__(256) void enc2c_kernel(const float* __restrict__ ep,
                                                    const float* __restrict__ b2,
                                                    float* __restrict__ e) {
  int idx = blockIdx.x * 256 + threadIdx.x;   // b*DSZ + i
  int b = idx >> 10, i = idx & (DSZ - 1);
  float s = b2[i];
#pragma unroll
  for (int kc = 0; kc < KS2; ++kc) s += ep[((size_t)(b * KS2 + kc)) * DSZ + i];
  e[idx] = s;
}

// -------- windows: win[b*T+t][j] = bf16(e[b][t+j])   (t+j < 1024 always)
__global__ void win_kernel(const float* __restrict__ e, __bf16* __restrict__ win) {
  int blk = blockIdx.x;               // b*512 + t
  int b = blk >> 9, t = blk & 511;
  const float* eb = e + b * DSZ;
  for (int j = threadIdx.x; j < 512; j += 256)
    win[(size_t)blk * 512 + j] = (__bf16)eb[t + j];
}

// -------- GEMM: C[m][n] = sum_k A[m][k]*B[n][k]  (both operands K-contiguous)
// BK=32 (round-2 proven loop), XCD-swizzled 1D grid.
// MODE 0: out bf16 row-major [M][N], + bias[n], optional gelu
// MODE 1: lm head: m=v, n=b*T+t -> outF[1 + b*V*T + v*T + t], guard v<VSZ,
//         fused softmax partials per 64-v stripe; LDS-restaged aligned stores
template<int MODE, int GELU>
__global__ __launch_bounds__(256) void gemm128(
    const __bf16* __restrict__ A, const __bf16* __restrict__ Bm,
    const float* __restrict__ bias, __bf16* __restrict__ outB,
    float* __restrict__ outF, float* __restrict__ pm, float* __restrict__ ps,
    int NT, int M, int N, int K) {
  __shared__ __align__(16) char SM[17024];    // smA 8K | smB 8K; epilogue reuses as f32 [32][132]
  char* smA = SM;
  char* smB = SM + 8192;
  float* epi = (float*)SM;
  const int tid = threadIdx.x;
  const int lane = tid & 63;
  const int wave = tid >> 6;
  const int wr = (wave >> 1) * 64, wc = (wave & 1) * 64;
  const int l15 = lane & 15, l4 = lane >> 4;

  // XCD-aware block swizzle (gridDim.x always divisible by 8 here)
  const int cpx = gridDim.x >> 3;
  const int wg = (blockIdx.x & 7) * cpx + (blockIdx.x >> 3);
  const int m0 = (wg / NT) * 128, n0 = (wg % NT) * 128;

  f32x4 acc[4][4];
#pragma unroll
  for (int i = 0; i < 4; ++i)
#pragma unroll
    for (int j = 0; j < 4; ++j) acc[i][j] = (f32x4){0.f, 0.f, 0.f, 0.f};

  const int srow = tid >> 2;          // 0..63
  const int scol = (tid & 3) * 8;     // k-elem offset
  const __bf16* Ag = A + (size_t)(m0 + srow) * K + scol;
  const __bf16* Bg = Bm + (size_t)(n0 + srow) * K + scol;

  for (int k0 = 0; k0 < K; k0 += 32) {
#pragma unroll
    for (int it = 0; it < 2; ++it) {
      GLD16(Ag + (size_t)it * 64 * K + k0, smA + it * 4096 + wave * 1024);
      GLD16(Bg + (size_t)it * 64 * K + k0, smB + it * 4096 + wave * 1024);
    }
    __syncthreads();
    bf16x8 af[4], bfr[4];
#pragma unroll
    for (int mi = 0; mi < 4; ++mi)
      af[mi] = *(const bf16x8*)(smA + (wr + mi * 16 + l15) * 64 + l4 * 16);
#pragma unroll
    for (int ni = 0; ni < 4; ++ni)
      bfr[ni] = *(const bf16x8*)(smB + (wc + ni * 16 + l15) * 64 + l4 * 16);
#pragma unroll
    for (int mi = 0; mi < 4; ++mi)
#pragma unroll
      for (int ni = 0; ni < 4; ++ni)
        acc[mi][ni] = __builtin_amdgcn_mfma_f32_16x16x32_bf16(af[mi], bfr[ni], acc[mi][ni], 0, 0, 0);
    __syncthreads();
  }

  if (MODE == 0) {
#pragma unroll
    for (int ni = 0; ni < 4; ++ni) {
      int n = n0 + wc + ni * 16 + l15;
      float bv = bias[n];
#pragma unroll
      for (int mi = 0; mi < 4; ++mi) {
#pragma unroll
        for (int r = 0; r < 4; ++r) {
          int m = m0 + wr + mi * 16 + l4 * 4 + r;
          float v = acc[mi][ni][r] + bv;
          if (GELU) v = gelu_f(v);
          outB[(size_t)m * N + n] = (__bf16)v;
        }
      }
    }
  } else {
    // ---- fused softmax partials (register-only + pm/ps)
    const int ch = (m0 + wr) >> 6;   // global 64-v stripe index
#pragma unroll
    for (int ni = 0; ni < 4; ++ni) {
      int n = n0 + wc + ni * 16 + l15;   // pos = b*T + t
      float mloc = -1e30f, sloc = 0.f;
#pragma unroll
      for (int mi = 0; mi < 4; ++mi) {
        int vbase = m0 + wr + mi * 16 + l4 * 4;
#pragma unroll
        for (int r = 0; r < 4; ++r) {
          if (vbase + r < VSZ) mloc = fmaxf(mloc, acc[mi][ni][r]);
        }
      }
#pragma unroll
      for (int mi = 0; mi < 4; ++mi) {
        int vbase = m0 + wr + mi * 16 + l4 * 4;
#pragma unroll
        for (int r = 0; r < 4; ++r) {
          if (vbase + r < VSZ) sloc += __expf(acc[mi][ni][r] - mloc);
        }
      }
#pragma unroll
      for (int off = 16; off <= 32; off <<= 1) {
        float mo = __shfl_xor(mloc, off, 64);
        float so = __shfl_xor(sloc, off, 64);
        float nm = fmaxf(mloc, mo);
        sloc = sloc * __expf(mloc - nm) + so * __expf(mo - nm);
        mloc = nm;
      }
      if (l4 == 0) {
        pm[(size_t)ch * NPOS + n] = mloc;
        ps[(size_t)ch * NPOS + n] = sloc;
      }
    }

    // ---- LDS-restaged aligned logits store: 4 quarters of 32 v-rows
    const int bb = n0 >> 9, t0 = n0 & 511;
    float* outG = outF + 1 + (size_t)bb * VSZ * TSZ + t0;
    const int trow = tid >> 5;          // 0..7
    const int lofs = (tid & 31) * 4;    // float offset within 128-t row
#pragma unroll
    for (int q = 0; q < 4; ++q) {
      __syncthreads();                  // previous quarter's reads done / K-loop done
      if ((wave >> 1) == (q >> 1)) {    // the 2 waves owning this 32-row band
        const int miBase = (q & 1) * 2;
#pragma unroll
        for (int mi2 = 0; mi2 < 2; ++mi2) {
#pragma unroll
          for (int ni = 0; ni < 4; ++ni) {
#pragma unroll
            for (int r = 0; r < 4; ++r)
              epi[(mi2 * 16 + l4 * 4 + r) * 132 + wc + ni * 16 + l15] =
                  acc[miBase + mi2][ni][r];
          }
        }
      }
      __syncthreads();
#pragma unroll
      for (int p = 0; p < 4; ++p) {
        int row = p * 8 + trow;
        int v = m0 + q * 32 + row;
        if (v < VSZ) {
          f32x4 val = *(const f32x4*)&epi[row * 132 + lofs];
          float* gp = outG + (size_t)v * TSZ + lofs;
          gp[0] = val[0]; gp[1] = val[1]; gp[2] = val[2]; gp[3] = val[3];
        }
      }
    }
  }
}

// -------- merge softmax partials per position (4 independent chains for ILP)
__global__ __launch_bounds__(256) void lsemerge_kernel(const float* __restrict__ pm,
                                                       const float* __restrict__ ps,
                                                       const float* __restrict__ outF,
                                                       const int* __restrict__ labels,
                                                       float* __restrict__ contrib) {
  int pos = blockIdx.x * 256 + threadIdx.x;   // 0..2047
  float m[4] = {-1e30f, -1e30f, -1e30f, -1e30f};
  float s[4] = {0.f, 0.f, 0.f, 0.f};
  for (int c = 0; c < NCH - 2; c += 4) {      // NCH = 786 = 4*196 + 2
#pragma unroll
    for (int j = 0; j < 4; ++j) {
      float cm = pm[(size_t)(c + j) * NPOS + pos];
      float cs = ps[(size_t)(c + j) * NPOS + pos];
      float nm = fmaxf(m[j], cm);
      s[j] = s[j] * __expf(m[j] - nm) + cs * __expf(cm - nm);
      m[j] = nm;
    }
  }
#pragma unroll
  for (int j = 0; j < 2; ++j) {
    float cm = pm[(size_t)(NCH - 2 + j) * NPOS + pos];
    float cs = ps[(size_t)(NCH - 2 + j) * NPOS + pos];
    float nm = fmaxf(m[j], cm);
    s[j] = s[j] * __expf(m[j] - nm) + cs * __expf(cm - nm);
    m[j] = nm;
  }
#pragma unroll
  for (int j = 1; j < 4; ++j) {
    float nm = fmaxf(m[0], m[j]);
    s[0] = s[0] * __expf(m[0] - nm) + s[j] * __expf(m[j] - nm);
    m[0] = nm;
  }
  float lse = m[0] + logf(s[0]);
  int b = pos >> 9, t = pos & 511;
  int lab = labels[pos];
  float x = outF[1 + (size_t)b * VSZ * TSZ + (size_t)lab * TSZ + t];
  contrib[pos] = lse - x;
}

__global__ __launch_bounds__(256) void lossfinal_kernel(const float* __restrict__ contrib,
                                                        float* __restrict__ dout) {
  __shared__ float red[256];
  int tid = threadIdx.x;
  float a = 0.f;
  for (int i = tid; i < NPOS; i += 256) a += contrib[i];
  red[tid] = a;
  __syncthreads();
  for (int off = 128; off; off >>= 1) {
    if (tid < off) red[tid] += red[tid + off];
    __syncthreads();
  }
  if (tid == 0) dout[0] = red[0] / (float)NPOS;
}

extern "C" void kernel_launch(void* const* d_in, const int* in_sizes, int n_in,
                              void* d_out, int out_size, void* d_ws, size_t ws_size,
                              hipStream_t stream) {
  const int* input_ids = (const int*)d_in[0];
  const int* labels    = (const int*)d_in[1];
  const float* wte     = (const float*)d_in[2];
  const float* enc_w1  = (const float*)d_in[3];
  const float* enc_b1  = (const float*)d_in[4];
  const float* enc_w2  = (const float*)d_in[5];
  const float* enc_b2  = (const float*)d_in[6];
  const float* proj_w  = (const float*)d_in[7];
  const float* proj_b  = (const float*)d_in[8];
  const float* dec_w1  = (const float*)d_in[9];
  const float* dec_b1  = (const float*)d_in[10];
  const float* dec_w2  = (const float*)d_in[11];
  const float* dec_b2  = (const float*)d_in[12];
  const float* lm_w    = (const float*)d_in[13];
  float* outF = (float*)d_out;

  char* w = (char*)d_ws;
  size_t off = 0;
  __bf16* lmT   = (__bf16*)(w + off); off += (size_t)VPAD * DSZ * 2;      // 103.0 MB
  __bf16* w1T   = (__bf16*)(w + off); off += (size_t)HSZ * DSZ * 2;       // 8 MB
  __bf16* w2T   = (__bf16*)(w + off); off += (size_t)DSZ * HSZ * 2;       // 8 MB
  __bf16* projT = (__bf16*)(w + off); off += (size_t)DSZ * 512 * 2;       // 1 MB
  __bf16* win   = (__bf16*)(w + off); off += (size_t)2048 * 512 * 2;      // 2 MB
  __bf16* pbuf  = (__bf16*)(w + off); off += (size_t)2048 * DSZ * 2;      // 4 MB
  __bf16* abuf  = (__bf16*)(w + off); off += (size_t)2048 * HSZ * 2;      // 16 MB
  __bf16* dbuf  = (__bf16*)(w + off); off += (size_t)2048 * DSZ * 2;      // 4 MB
  float* e      = (float*)(w + off);  off += (size_t)BSZ * DSZ * 4;
  float* t1p    = (float*)(w + off);  off += (size_t)BSZ * KS1 * HSZ * 4;   // 512 KB
  float* ep     = (float*)(w + off);  off += (size_t)BSZ * KS2 * DSZ * 4;   // 256 KB
  float* contrib= (float*)(w + off);  off += (size_t)NPOS * 4;
  // softmax partials alias abuf (free after gemm3): 786*2048*4*2 = 12.9 MB <= 16 MB
  float* pm = (float*)abuf;
  float* ps = pm + (size_t)NCH * NPOS;
  (void)ws_size; (void)in_sizes; (void)n_in; (void)out_size;

  // weight transposes (f32 -> bf16, K-contiguous)
  transpose_conv64<<<dim3(VPAD / 64, DSZ / 64), 256, 0, stream>>>(lm_w, lmT, DSZ, VSZ, VPAD);
  transpose_conv64<<<dim3(HSZ / 64, DSZ / 64), 256, 0, stream>>>(dec_w1, w1T, DSZ, HSZ, HSZ);
  transpose_conv64<<<dim3(DSZ / 64, HSZ / 64), 256, 0, stream>>>(dec_w2, w2T, HSZ, DSZ, DSZ);
  transpose_conv64<<<dim3(DSZ / 64, 512 / 64), 256, 0, stream>>>(proj_w, projT, 512, DSZ, DSZ);

  // encoder on last token only (K-split for parallelism)
  enc1p_kernel<<<dim3(BSZ, HSZ / 256, KS1), 256, 0, stream>>>(input_ids, wte, enc_w1, t1p);
  enc2p_kernel<<<dim3(BSZ, DSZ / 256, KS2), 256, 0, stream>>>(t1p, enc_b1, enc_w2, ep);
  enc2c_kernel<<<dim3(BSZ * DSZ / 256), 256, 0, stream>>>(ep, enc_b2, e);
  win_kernel<<<2048, 256, 0, stream>>>(e, win);

  // GEMM chain (1D grids, all divisible by 8 for the XCD swizzle)
  gemm128<0, 0><<<128, 256, 0, stream>>>(win, projT, proj_b, pbuf, nullptr, nullptr, nullptr, 8, 2048, DSZ, 512);
  gemm128<0, 1><<<512, 256, 0, stream>>>(pbuf, w1T, dec_b1, abuf, nullptr, nullptr, nullptr, 32, 2048, HSZ, DSZ);
  gemm128<0, 0><<<128, 256, 0, stream>>>(abuf, w2T, dec_b2, dbuf, nullptr, nullptr, nullptr, 8, 2048, DSZ, HSZ);
  // lm head with fused softmax partials; grid = 393*16 = 6288, m = v-tiles
  gemm128<1, 0><<<6288, 256, 0, stream>>>(lmT, dbuf, nullptr, nullptr, outF, pm, ps, 16, VPAD, 2048, DSZ);

  // loss: merge partials + mean
  lsemerge_kernel<<<dim3(NPOS / 256), 256, 0, stream>>>(pm, ps, outF, labels, contrib);
  lossfinal_kernel<<<1, 256, 0, stream>>>(contrib, outF);
}